// Round 5
// baseline (2398.920 us; speedup 1.0000x reference)
//
#include <hip/hip_runtime.h>
#include <hip/hip_bf16.h>
#include <math.h>
#include <cstddef>

#define LSEQ 8000
#define EPS 1e-5f

typedef unsigned short ushort_t;
typedef __attribute__((ext_vector_type(8))) short s16x8;   // 8 bf16 = 4 VGPR
typedef __attribute__((ext_vector_type(4))) float f32x4;   // MFMA C/D

__device__ __forceinline__ ushort_t f2bf(float f) {
    union { float f; unsigned u; } x; x.f = f;
    unsigned r = x.u + 0x7FFFu + ((x.u >> 16) & 1u);   // RNE
    return (ushort_t)(r >> 16);
}
__device__ __forceinline__ float bf2f(ushort_t h) {
    union { unsigned u; float f; } x; x.u = ((unsigned)h) << 16;
    return x.f;
}

// ---------------- fp32 -> (bf16 hi, bf16 lo) split convert (w_exp) ----------------
__global__ void cvt_split_kernel(const float* __restrict__ src,
                                 ushort_t* __restrict__ hi, ushort_t* __restrict__ lo, int n) {
    for (int i = blockIdx.x * blockDim.x + threadIdx.x; i < n; i += gridDim.x * blockDim.x) {
        float v = src[i];
        ushort_t h = f2bf(v);
        hi[i] = h;
        lo[i] = f2bf(v - bf2f(h));
    }
}

// ---------------- plain stats over x (front GN) ----------------
__global__ __launch_bounds__(256)
void stats_plain(const float* __restrict__ in, int C, float* __restrict__ stats) {
    int b = blockIdx.y, c = blockIdx.x;
    const float* row = in + ((size_t)b * C + c) * LSEQ;
    float s = 0.f, sq = 0.f;
    for (int l4 = threadIdx.x * 4; l4 < LSEQ; l4 += 1024) {
        float4 v = *(const float4*)(row + l4);
        s += v.x + v.y + v.z + v.w;
        sq += v.x * v.x + v.y * v.y + v.z * v.z + v.w * v.w;
    }
    for (int off = 32; off > 0; off >>= 1) {
        s += __shfl_down(s, off, 64);
        sq += __shfl_down(sq, off, 64);
    }
    __shared__ float red[4][2];
    int wid = threadIdx.x >> 6, lane = threadIdx.x & 63;
    if (lane == 0) { red[wid][0] = s; red[wid][1] = sq; }
    __syncthreads();
    if (threadIdx.x == 0) {
        float ts = red[0][0] + red[1][0] + red[2][0] + red[3][0];
        float tq = red[0][1] + red[1][1] + red[2][1] + red[3][1];
        atomicAdd(&stats[b * 2 + 0], ts);
        atomicAdd(&stats[b * 2 + 1], tq);
    }
}

// ---------------- kernel A: dwconv+PReLU once, write h split bf16 hi/lo in
// granule layout [b][g=16][L][8], and accumulate GN stats ----------------
// grid (25 l-chunks of 320, 16 granules, 4 b), 320 threads.
__global__ __launch_bounds__(320)
void conv_split_stats(const float* __restrict__ in,   // [4][128][L]
                      const float* __restrict__ dw,   // [128][3]
                      const float* __restrict__ pa,   // [128]
                      int dil,
                      ushort_t* __restrict__ hH, ushort_t* __restrict__ hL,
                      float* __restrict__ stats)      // [4][2] pre-zeroed
{
    __shared__ float Ls[8][576];    // rows g*8..+7, cols l0-256 .. l0+319
    __shared__ float dwl[8][4];
    __shared__ float red[5][2];
    int tid = threadIdx.x;
    int g = blockIdx.y, b = blockIdx.z;
    int l0 = blockIdx.x * 320;
    const float* base = in + ((size_t)b * 128 + g * 8) * LSEQ;

    for (int idx = tid; idx < 8 * 144; idx += 320) {
        int r = idx / 144, f4 = idx % 144;
        int off = l0 - 256 + f4 * 4;
        const float* rp = base + (size_t)r * LSEQ;
        float4 v;
        if (off >= 0) {
            v = *(const float4*)(rp + off);
        } else {
            v.x = 0.f;
            v.y = (off + 1 >= 0) ? rp[off + 1] : 0.f;
            v.z = (off + 2 >= 0) ? rp[off + 2] : 0.f;
            v.w = (off + 3 >= 0) ? rp[off + 3] : 0.f;
        }
        *(float4*)&Ls[r][f4 * 4] = v;
    }
    if (tid < 32) {
        int j = tid >> 2, q = tid & 3;
        dwl[j][q] = (q < 3) ? dw[(g * 8 + j) * 3 + q] : pa[g * 8 + j];
    }
    __syncthreads();

    float s = 0.f, sq = 0.f;
    s16x8 hv, lv;
    int lt = tid;  // 0..319
#pragma unroll
    for (int j = 0; j < 8; j++) {
        float x2 = Ls[j][256 + lt];
        float x1 = Ls[j][256 + lt - dil];
        float x0 = Ls[j][256 + lt - 2 * dil];
        float h = fmaf(dwl[j][0], x0, fmaf(dwl[j][1], x1, dwl[j][2] * x2));
        h = h > 0.f ? h : dwl[j][3] * h;
        s += h; sq += h * h;
        ushort_t hb = f2bf(h);
        hv[j] = (short)hb;
        lv[j] = (short)f2bf(h - bf2f(hb));
    }
    size_t o = (((size_t)b * 16 + g) * LSEQ + l0 + lt) * 8;
    *(s16x8*)(hH + o) = hv;
    *(s16x8*)(hL + o) = lv;

    for (int off = 32; off > 0; off >>= 1) {
        s += __shfl_down(s, off, 64);
        sq += __shfl_down(sq, off, 64);
    }
    int wid = tid >> 6, lane = tid & 63;
    if (lane == 0) { red[wid][0] = s; red[wid][1] = sq; }
    __syncthreads();
    if (tid == 0) {
        float ts = 0.f, tq = 0.f;
        for (int i = 0; i < 5; i++) { ts += red[i][0]; tq += red[i][1]; }
        atomicAdd(&stats[b * 2 + 0], ts);
        atomicAdd(&stats[b * 2 + 1], tq);
    }
}

// ---------------- fold kernel: W' = W*s[c] (split bf16), bias = W.t ----------------
// grid (4 b), 256 threads.
template<int KT>
__global__ __launch_bounds__(256)
void fold_kernel(const float* __restrict__ W,     // [128][KT]
                 const float* __restrict__ gam, const float* __restrict__ bet,
                 const float* __restrict__ stats, // [4][2]
                 float invCN,
                 ushort_t* __restrict__ WH, ushort_t* __restrict__ WL, // [4][128][KT]
                 float* __restrict__ bias)        // [4][128]
{
    __shared__ float s_s[KT], t_s[KT];
    int b = blockIdx.x, tid = threadIdx.x;
    float m = stats[b * 2 + 0] * invCN;
    float var = stats[b * 2 + 1] * invCN - m * m;
    float rs = rsqrtf(var + EPS);
    for (int c = tid; c < KT; c += 256) {
        float sc = rs * gam[c];
        s_s[c] = sc;
        t_s[c] = bet[c] - m * sc;
    }
    __syncthreads();
    for (int idx = tid; idx < 128 * KT; idx += 256) {
        int c = idx & (KT - 1);
        float v = W[idx] * s_s[c];
        ushort_t hb = f2bf(v);
        WH[(size_t)b * 128 * KT + idx] = hb;
        WL[(size_t)b * 128 * KT + idx] = f2bf(v - bf2f(hb));
    }
    if (tid < 128) {
        float acc = 0.f;
        const float* wr = W + (size_t)tid * KT;
        for (int c = 0; c < KT; c++) acc = fmaf(wr[c], t_s[c], acc);
        bias[b * 128 + tid] = acc;
    }
}

// ---------------- fused MFMA GEMM, split-bf16 3-term ----------------
// STAGE 0: copy pre-split h granules (hH/hL). STAGE 1: split from fp32 inF.
// OTILES>1: stage once, loop output tiles (expansion). WPERB: W folded per-sample.
template<int KTOT, int MROWS, int OTILES, int STAGE, bool WPERB, bool BIAS, bool HASRES, bool SIG>
__global__ __launch_bounds__(256)
void gemm_mfma(const float* __restrict__ inF,
               const ushort_t* __restrict__ hH, const ushort_t* __restrict__ hL,
               const ushort_t* __restrict__ WH, const ushort_t* __restrict__ WL,
               const float* __restrict__ bias,  // [4][128]
               const float* __restrict__ res,
               float* __restrict__ outp)
{
    constexpr int NCHUNK = KTOT / 128;
    static_assert(OTILES == 1 || NCHUNK == 1, "");
    __shared__ ushort_t hsH[16 * 64 * 8];   // [gk][slot-col][8], 16 KB
    __shared__ ushort_t hsL[16 * 64 * 8];

    int tid = threadIdx.x;
    int b = blockIdx.z;
    int l0 = blockIdx.x * 64;
    int wave = tid >> 6, lane = tid & 63;
    int lg = lane >> 4, lr = lane & 15;
    int rowoff = (wave >> 1) * 64, coloff = (wave & 1) * 32;

    f32x4 acc[4][2];

    for (int ot = 0; ot < OTILES; ot++) {
#pragma unroll
        for (int rf = 0; rf < 4; rf++)
#pragma unroll
            for (int cf = 0; cf < 2; cf++)
                acc[rf][cf] = (f32x4){0.f, 0.f, 0.f, 0.f};

        for (int kc = 0; kc < NCHUNK; kc++) {
            if (ot == 0) {
                __syncthreads();
                if constexpr (STAGE == 0) {
                    int scol = lane;
#pragma unroll
                    for (int gi = 0; gi < 4; gi++) {
                        int g = wave * 4 + gi;
                        size_t src = (((size_t)b * 16 + g) * LSEQ + l0 + scol) * 8;
                        s16x8 hv = *(const s16x8*)(hH + src);
                        s16x8 lv = *(const s16x8*)(hL + src);
                        int slot = (g * 64 + (scol ^ ((g & 3) << 1))) * 8;
                        *(s16x8*)&hsH[slot] = hv;
                        *(s16x8*)&hsL[slot] = lv;
                    }
                } else {
                    int scol = tid & 63;
                    int sg0 = (tid >> 6) * 4;
#pragma unroll
                    for (int gi = 0; gi < 4; gi++) {
                        int gk = sg0 + gi;
                        s16x8 hv, lv;
#pragma unroll
                        for (int j = 0; j < 8; j++) {
                            int c = kc * 128 + gk * 8 + j;
                            float v = inF[((size_t)b * KTOT + c) * LSEQ + l0 + scol];
                            ushort_t hb = f2bf(v);
                            hv[j] = (short)hb;
                            lv[j] = (short)f2bf(v - bf2f(hb));
                        }
                        int slot = (gk * 64 + (scol ^ ((gk & 3) << 1))) * 8;
                        *(s16x8*)&hsH[slot] = hv;
                        *(s16x8*)&hsL[slot] = lv;
                    }
                }
                __syncthreads();
            }

#pragma unroll
            for (int ks = 0; ks < 4; ks++) {
                s16x8 aH[4], aL[4];
#pragma unroll
                for (int rf = 0; rf < 4; rf++) {
                    int row = ot * 128 + rowoff + rf * 16 + lr;
                    size_t woff = ((size_t)(WPERB ? b : 0) * MROWS + row) * KTOT
                                  + kc * 128 + ks * 32 + lg * 8;
                    aH[rf] = *(const s16x8*)(WH + woff);
                    aL[rf] = *(const s16x8*)(WL + woff);
                }
#pragma unroll
                for (int cf = 0; cf < 2; cf++) {
                    int col = coloff + cf * 16 + lr;
                    int gk = ks * 4 + lg;
                    int slot = (gk * 64 + (col ^ ((gk & 3) << 1))) * 8;
                    s16x8 bH = *(const s16x8*)&hsH[slot];
                    s16x8 bL = *(const s16x8*)&hsL[slot];
#pragma unroll
                    for (int rf = 0; rf < 4; rf++) {
                        acc[rf][cf] = __builtin_amdgcn_mfma_f32_16x16x32_bf16(aH[rf], bH, acc[rf][cf], 0, 0, 0);
                        acc[rf][cf] = __builtin_amdgcn_mfma_f32_16x16x32_bf16(aH[rf], bL, acc[rf][cf], 0, 0, 0);
                        acc[rf][cf] = __builtin_amdgcn_mfma_f32_16x16x32_bf16(aL[rf], bH, acc[rf][cf], 0, 0, 0);
                    }
                }
            }
        }

        // epilogue for this o-tile
#pragma unroll
        for (int rf = 0; rf < 4; rf++) {
#pragma unroll
            for (int cf = 0; cf < 2; cf++) {
#pragma unroll
                for (int r = 0; r < 4; r++) {
                    int rloc = rowoff + rf * 16 + lg * 4 + r;
                    int row = ot * 128 + rloc;
                    int col = l0 + coloff + cf * 16 + lr;
                    size_t idx = ((size_t)b * MROWS + row) * LSEQ + col;
                    float v = acc[rf][cf][r];
                    if (BIAS) v += bias[b * 128 + rloc];
                    if (HASRES) v += res[idx];
                    if (SIG) v = 1.f / (1.f + __expf(-v));
                    outp[idx] = v;
                }
            }
        }
    }
}

extern "C" void kernel_launch(void* const* d_in, const int* in_sizes, int n_in,
                              void* d_out, int out_size, void* d_ws, size_t ws_size,
                              hipStream_t stream) {
    const float* x      = (const float*)d_in[0];
    const float* gn_g   = (const float*)d_in[1];
    const float* gn_b   = (const float*)d_in[2];
    const float* w_comp = (const float*)d_in[3];
    const float* dw_w   = (const float*)d_in[4];
    const float* pr_a   = (const float*)d_in[5];
    const float* tn_g   = (const float*)d_in[6];
    const float* tn_b   = (const float*)d_in[7];
    const float* pw_w   = (const float*)d_in[8];
    const float* w_exp  = (const float*)d_in[9];
    float* out = (float*)d_out;

    const size_t ACTF = (size_t)4 * 128 * LSEQ;     // 4,096,000
    float* bufA = (float*)d_ws;
    float* bufB = bufA + ACTF;
    ushort_t* hH   = (ushort_t*)(bufB + ACTF);      // [4][16][L][8]
    ushort_t* hL   = hH + ACTF;
    ushort_t* wcFH = hL + ACTF;                     // [4][128][512]
    ushort_t* wcFL = wcFH + (size_t)4 * 128 * 512;
    ushort_t* wfH  = wcFL + (size_t)4 * 128 * 512;  // [4][128][128]
    ushort_t* wfL  = wfH + (size_t)4 * 128 * 128;
    ushort_t* weH  = wfL + (size_t)4 * 128 * 128;   // [1024][128]
    ushort_t* weL  = weH + (size_t)1024 * 128;
    float* biasF = (float*)(weL + (size_t)1024 * 128);  // [4][128]
    float* biasM = biasF + 512;                          // [4][128]
    float* stats = biasM + 512;                          // [25][4][2]

    hipMemsetAsync(stats, 0, 25 * 4 * 2 * sizeof(float), stream);

    cvt_split_kernel<<<dim3(256), 256, 0, stream>>>(w_exp, weH, weL, 1024 * 128);

    // front: GN(x) folded into w_comp
    stats_plain<<<dim3(512, 4), 256, 0, stream>>>(x, 512, stats);
    fold_kernel<512><<<dim3(4), 256, 0, stream>>>(
        w_comp, gn_g, gn_b, stats, 1.f / (512.f * (float)LSEQ), wcFH, wcFL, biasF);
    gemm_mfma<512, 128, 1, 1, true, true, false, false><<<dim3(125, 1, 4), 256, 0, stream>>>(
        x, nullptr, nullptr, wcFH, wcFL, biasF, nullptr, bufA);

    float* cur = bufA;
    float* nxt = bufB;
    for (int i = 0; i < 24; i++) {
        int dil = 1 << (i & 7);
        float* st = stats + (size_t)(1 + i) * 8;
        conv_split_stats<<<dim3(25, 16, 4), 320, 0, stream>>>(
            cur, dw_w + (size_t)i * 384, pr_a + (size_t)i * 128, dil, hH, hL, st);
        fold_kernel<128><<<dim3(4), 256, 0, stream>>>(
            pw_w + (size_t)i * 16384, tn_g + (size_t)i * 128, tn_b + (size_t)i * 128,
            st, 1.f / (128.f * (float)LSEQ), wfH, wfL, biasM);
        gemm_mfma<128, 128, 1, 0, true, true, true, false><<<dim3(125, 1, 4), 256, 0, stream>>>(
            nullptr, hH, hL, wfH, wfL, biasM, cur, nxt);
        float* tmp = cur; cur = nxt; nxt = tmp;
    }

    // back: expansion (128 -> 1024) + sigmoid, o-tiles looped in-block
    gemm_mfma<128, 1024, 8, 1, false, false, false, true><<<dim3(125, 1, 4), 256, 0, stream>>>(
        cur, nullptr, nullptr, weH, weL, nullptr, nullptr, out);
}

// Round 6
// 1906.407 us; speedup vs baseline: 1.2583x; 1.2583x over previous
//
#include <hip/hip_runtime.h>
#include <hip/hip_bf16.h>
#include <math.h>
#include <cstddef>

#define LSEQ 8000
#define EPS 1e-5f

typedef unsigned short ushort_t;
typedef __attribute__((ext_vector_type(8))) short s16x8;   // 8 bf16 = 4 VGPR
typedef __attribute__((ext_vector_type(4))) float f32x4;   // MFMA C/D
typedef __attribute__((ext_vector_type(4))) unsigned short us16x4;

__device__ __forceinline__ ushort_t f2bf(float f) {
    union { float f; unsigned u; } x; x.f = f;
    unsigned r = x.u + 0x7FFFu + ((x.u >> 16) & 1u);   // RNE
    return (ushort_t)(r >> 16);
}
__device__ __forceinline__ float bf2f(ushort_t h) {
    union { unsigned u; float f; } x; x.u = ((unsigned)h) << 16;
    return x.f;
}

// ---------------- fp32 -> (bf16 hi, bf16 lo) split convert (w_exp) ----------------
__global__ void cvt_split_kernel(const float* __restrict__ src,
                                 ushort_t* __restrict__ hi, ushort_t* __restrict__ lo, int n) {
    for (int i = blockIdx.x * blockDim.x + threadIdx.x; i < n; i += gridDim.x * blockDim.x) {
        float v = src[i];
        ushort_t h = f2bf(v);
        hi[i] = h;
        lo[i] = f2bf(v - bf2f(h));
    }
}

// ---------------- plain stats over x (front GN) ----------------
__global__ __launch_bounds__(256)
void stats_plain(const float* __restrict__ in, int C, float* __restrict__ stats) {
    int b = blockIdx.y, c = blockIdx.x;
    const float* row = in + ((size_t)b * C + c) * LSEQ;
    float s = 0.f, sq = 0.f;
    for (int l4 = threadIdx.x * 4; l4 < LSEQ; l4 += 1024) {
        float4 v = *(const float4*)(row + l4);
        s += v.x + v.y + v.z + v.w;
        sq += v.x * v.x + v.y * v.y + v.z * v.z + v.w * v.w;
    }
    for (int off = 32; off > 0; off >>= 1) {
        s += __shfl_down(s, off, 64);
        sq += __shfl_down(sq, off, 64);
    }
    __shared__ float red[4][2];
    int wid = threadIdx.x >> 6, lane = threadIdx.x & 63;
    if (lane == 0) { red[wid][0] = s; red[wid][1] = sq; }
    __syncthreads();
    if (threadIdx.x == 0) {
        float ts = red[0][0] + red[1][0] + red[2][0] + red[3][0];
        float tq = red[0][1] + red[1][1] + red[2][1] + red[3][1];
        atomicAdd(&stats[b * 2 + 0], ts);
        atomicAdd(&stats[b * 2 + 1], tq);
    }
}

// ---------------- kernel A: dwconv+PReLU once, write h split bf16 hi/lo in
// granule layout [b][g=16][L][8], and accumulate GN stats ----------------
// grid (25 l-chunks of 320, 16 granules, 4 b), 320 threads.
__global__ __launch_bounds__(320)
void conv_split_stats(const float* __restrict__ in,   // [4][128][L]
                      const float* __restrict__ dw,   // [128][3]
                      const float* __restrict__ pa,   // [128]
                      int dil,
                      ushort_t* __restrict__ hH, ushort_t* __restrict__ hL,
                      float* __restrict__ stats)      // [4][2] pre-zeroed
{
    __shared__ float Ls[8][576];    // rows g*8..+7, cols l0-256 .. l0+319
    __shared__ float dwl[8][4];
    __shared__ float red[5][2];
    int tid = threadIdx.x;
    int g = blockIdx.y, b = blockIdx.z;
    int l0 = blockIdx.x * 320;
    const float* base = in + ((size_t)b * 128 + g * 8) * LSEQ;

    for (int idx = tid; idx < 8 * 144; idx += 320) {
        int r = idx / 144, f4 = idx % 144;
        int off = l0 - 256 + f4 * 4;
        const float* rp = base + (size_t)r * LSEQ;
        float4 v;
        if (off >= 0) {
            v = *(const float4*)(rp + off);
        } else {
            v.x = 0.f;
            v.y = (off + 1 >= 0) ? rp[off + 1] : 0.f;
            v.z = (off + 2 >= 0) ? rp[off + 2] : 0.f;
            v.w = (off + 3 >= 0) ? rp[off + 3] : 0.f;
        }
        *(float4*)&Ls[r][f4 * 4] = v;
    }
    if (tid < 32) {
        int j = tid >> 2, q = tid & 3;
        dwl[j][q] = (q < 3) ? dw[(g * 8 + j) * 3 + q] : pa[g * 8 + j];
    }
    __syncthreads();

    float s = 0.f, sq = 0.f;
    s16x8 hv, lv;
    int lt = tid;  // 0..319
#pragma unroll
    for (int j = 0; j < 8; j++) {
        float x2 = Ls[j][256 + lt];
        float x1 = Ls[j][256 + lt - dil];
        float x0 = Ls[j][256 + lt - 2 * dil];
        float h = fmaf(dwl[j][0], x0, fmaf(dwl[j][1], x1, dwl[j][2] * x2));
        h = h > 0.f ? h : dwl[j][3] * h;
        s += h; sq += h * h;
        ushort_t hb = f2bf(h);
        hv[j] = (short)hb;
        lv[j] = (short)f2bf(h - bf2f(hb));
    }
    size_t o = (((size_t)b * 16 + g) * LSEQ + l0 + lt) * 8;
    *(s16x8*)(hH + o) = hv;
    *(s16x8*)(hL + o) = lv;

    for (int off = 32; off > 0; off >>= 1) {
        s += __shfl_down(s, off, 64);
        sq += __shfl_down(sq, off, 64);
    }
    int wid = tid >> 6, lane = tid & 63;
    if (lane == 0) { red[wid][0] = s; red[wid][1] = sq; }
    __syncthreads();
    if (tid == 0) {
        float ts = 0.f, tq = 0.f;
        for (int i = 0; i < 5; i++) { ts += red[i][0]; tq += red[i][1]; }
        atomicAdd(&stats[b * 2 + 0], ts);
        atomicAdd(&stats[b * 2 + 1], tq);
    }
}

// ---------------- fold kernel: W' = W*s[c] (split bf16), bias[o] = sum_c W[o][c]*t[c] --
// grid (16 chunks, 4 b), 256 threads. Each block: 8 W-rows fold + 8 bias dots.
template<int KT>
__global__ __launch_bounds__(256)
void fold_kernel(const float* __restrict__ W,     // [128][KT]
                 const float* __restrict__ gam, const float* __restrict__ bet,
                 const float* __restrict__ stats, // [4][2]
                 float invCN,
                 ushort_t* __restrict__ WH, ushort_t* __restrict__ WL, // [4][128][KT]
                 float* __restrict__ bias)        // [4][128]
{
    int chunk = blockIdx.x, b = blockIdx.y, tid = threadIdx.x;
    float m = stats[b * 2 + 0] * invCN;
    float var = stats[b * 2 + 1] * invCN - m * m;
    float rs = rsqrtf(var + EPS);

    // ---- fold 8 rows (8*KT elements), float4 loads, fully unrolled ----
    size_t base = (size_t)chunk * 8 * KT;
    ushort_t* WHb = WH + (size_t)b * 128 * KT;
    ushort_t* WLb = WL + (size_t)b * 128 * KT;
#pragma unroll
    for (int it = 0; it < (8 * KT) / 1024; ++it) {
        int i = it * 1024 + tid * 4;
        int c = i & (KT - 1);
        float4 w4 = *(const float4*)(W + base + i);
        float4 g4 = *(const float4*)(gam + c);
        float v0 = w4.x * g4.x * rs, v1 = w4.y * g4.y * rs;
        float v2 = w4.z * g4.z * rs, v3 = w4.w * g4.w * rs;
        us16x4 hv, lv;
        ushort_t h0 = f2bf(v0); hv[0] = h0; lv[0] = f2bf(v0 - bf2f(h0));
        ushort_t h1 = f2bf(v1); hv[1] = h1; lv[1] = f2bf(v1 - bf2f(h1));
        ushort_t h2 = f2bf(v2); hv[2] = h2; lv[2] = f2bf(v2 - bf2f(h2));
        ushort_t h3 = f2bf(v3); hv[3] = h3; lv[3] = f2bf(v3 - bf2f(h3));
        *(us16x4*)(WHb + base + i) = hv;
        *(us16x4*)(WLb + base + i) = lv;
    }

    // ---- bias: 8 rows, 32 lanes per row, KT/32 elements each (float4) ----
    int rg = tid >> 5;          // 0..7
    int lane32 = tid & 31;
    int row = chunk * 8 + rg;
    const float* wr = W + (size_t)row * KT;
    float acc = 0.f;
#pragma unroll
    for (int it = 0; it < KT / 128; ++it) {
        int c = it * 128 + lane32 * 4;
        float4 w4 = *(const float4*)(wr + c);
        float4 g4 = *(const float4*)(gam + c);
        float4 b4 = *(const float4*)(bet + c);
        acc += w4.x * (b4.x - m * rs * g4.x);
        acc += w4.y * (b4.y - m * rs * g4.y);
        acc += w4.z * (b4.z - m * rs * g4.z);
        acc += w4.w * (b4.w - m * rs * g4.w);
    }
#pragma unroll
    for (int off = 16; off > 0; off >>= 1)
        acc += __shfl_down(acc, off, 32);
    if (lane32 == 0) bias[b * 128 + row] = acc;
}

// ---------------- fused MFMA GEMM, split-bf16 3-term ----------------
// STAGE 0: copy pre-split h granules (hH/hL). STAGE 1: split from fp32 inF.
// OTILES>1: stage once, loop output tiles (expansion). WPERB: W folded per-sample.
template<int KTOT, int MROWS, int OTILES, int STAGE, bool WPERB, bool BIAS, bool HASRES, bool SIG>
__global__ __launch_bounds__(256)
void gemm_mfma(const float* __restrict__ inF,
               const ushort_t* __restrict__ hH, const ushort_t* __restrict__ hL,
               const ushort_t* __restrict__ WH, const ushort_t* __restrict__ WL,
               const float* __restrict__ bias,  // [4][128]
               const float* __restrict__ res,
               float* __restrict__ outp)
{
    constexpr int NCHUNK = KTOT / 128;
    static_assert(OTILES == 1 || NCHUNK == 1, "");
    __shared__ ushort_t hsH[16 * 64 * 8];   // [gk][slot-col][8], 16 KB
    __shared__ ushort_t hsL[16 * 64 * 8];

    int tid = threadIdx.x;
    int b = blockIdx.z;
    int l0 = blockIdx.x * 64;
    int wave = tid >> 6, lane = tid & 63;
    int lg = lane >> 4, lr = lane & 15;
    int rowoff = (wave >> 1) * 64, coloff = (wave & 1) * 32;

    f32x4 acc[4][2];

    for (int ot = 0; ot < OTILES; ot++) {
#pragma unroll
        for (int rf = 0; rf < 4; rf++)
#pragma unroll
            for (int cf = 0; cf < 2; cf++)
                acc[rf][cf] = (f32x4){0.f, 0.f, 0.f, 0.f};

        for (int kc = 0; kc < NCHUNK; kc++) {
            if (ot == 0) {
                __syncthreads();
                if constexpr (STAGE == 0) {
                    int scol = lane;
#pragma unroll
                    for (int gi = 0; gi < 4; gi++) {
                        int g = wave * 4 + gi;
                        size_t src = (((size_t)b * 16 + g) * LSEQ + l0 + scol) * 8;
                        s16x8 hv = *(const s16x8*)(hH + src);
                        s16x8 lv = *(const s16x8*)(hL + src);
                        int slot = (g * 64 + (scol ^ ((g & 3) << 1))) * 8;
                        *(s16x8*)&hsH[slot] = hv;
                        *(s16x8*)&hsL[slot] = lv;
                    }
                } else {
                    int scol = tid & 63;
                    int sg0 = (tid >> 6) * 4;
#pragma unroll
                    for (int gi = 0; gi < 4; gi++) {
                        int gk = sg0 + gi;
                        s16x8 hv, lv;
#pragma unroll
                        for (int j = 0; j < 8; j++) {
                            int c = kc * 128 + gk * 8 + j;
                            float v = inF[((size_t)b * KTOT + c) * LSEQ + l0 + scol];
                            ushort_t hb = f2bf(v);
                            hv[j] = (short)hb;
                            lv[j] = (short)f2bf(v - bf2f(hb));
                        }
                        int slot = (gk * 64 + (scol ^ ((gk & 3) << 1))) * 8;
                        *(s16x8*)&hsH[slot] = hv;
                        *(s16x8*)&hsL[slot] = lv;
                    }
                }
                __syncthreads();
            }

#pragma unroll
            for (int ks = 0; ks < 4; ks++) {
                s16x8 aH[4], aL[4];
#pragma unroll
                for (int rf = 0; rf < 4; rf++) {
                    int row = ot * 128 + rowoff + rf * 16 + lr;
                    size_t woff = ((size_t)(WPERB ? b : 0) * MROWS + row) * KTOT
                                  + kc * 128 + ks * 32 + lg * 8;
                    aH[rf] = *(const s16x8*)(WH + woff);
                    aL[rf] = *(const s16x8*)(WL + woff);
                }
#pragma unroll
                for (int cf = 0; cf < 2; cf++) {
                    int col = coloff + cf * 16 + lr;
                    int gk = ks * 4 + lg;
                    int slot = (gk * 64 + (col ^ ((gk & 3) << 1))) * 8;
                    s16x8 bH = *(const s16x8*)&hsH[slot];
                    s16x8 bL = *(const s16x8*)&hsL[slot];
#pragma unroll
                    for (int rf = 0; rf < 4; rf++) {
                        acc[rf][cf] = __builtin_amdgcn_mfma_f32_16x16x32_bf16(aH[rf], bH, acc[rf][cf], 0, 0, 0);
                        acc[rf][cf] = __builtin_amdgcn_mfma_f32_16x16x32_bf16(aH[rf], bL, acc[rf][cf], 0, 0, 0);
                        acc[rf][cf] = __builtin_amdgcn_mfma_f32_16x16x32_bf16(aL[rf], bH, acc[rf][cf], 0, 0, 0);
                    }
                }
            }
        }

        // epilogue for this o-tile
#pragma unroll
        for (int rf = 0; rf < 4; rf++) {
#pragma unroll
            for (int cf = 0; cf < 2; cf++) {
#pragma unroll
                for (int r = 0; r < 4; r++) {
                    int rloc = rowoff + rf * 16 + lg * 4 + r;
                    int row = ot * 128 + rloc;
                    int col = l0 + coloff + cf * 16 + lr;
                    size_t idx = ((size_t)b * MROWS + row) * LSEQ + col;
                    float v = acc[rf][cf][r];
                    if (BIAS) v += bias[b * 128 + rloc];
                    if (HASRES) v += res[idx];
                    if (SIG) v = 1.f / (1.f + __expf(-v));
                    outp[idx] = v;
                }
            }
        }
    }
}

extern "C" void kernel_launch(void* const* d_in, const int* in_sizes, int n_in,
                              void* d_out, int out_size, void* d_ws, size_t ws_size,
                              hipStream_t stream) {
    const float* x      = (const float*)d_in[0];
    const float* gn_g   = (const float*)d_in[1];
    const float* gn_b   = (const float*)d_in[2];
    const float* w_comp = (const float*)d_in[3];
    const float* dw_w   = (const float*)d_in[4];
    const float* pr_a   = (const float*)d_in[5];
    const float* tn_g   = (const float*)d_in[6];
    const float* tn_b   = (const float*)d_in[7];
    const float* pw_w   = (const float*)d_in[8];
    const float* w_exp  = (const float*)d_in[9];
    float* out = (float*)d_out;

    const size_t ACTF = (size_t)4 * 128 * LSEQ;     // 4,096,000
    float* bufA = (float*)d_ws;
    float* bufB = bufA + ACTF;
    ushort_t* hH   = (ushort_t*)(bufB + ACTF);      // [4][16][L][8]
    ushort_t* hL   = hH + ACTF;
    ushort_t* wcFH = hL + ACTF;                     // [4][128][512]
    ushort_t* wcFL = wcFH + (size_t)4 * 128 * 512;
    ushort_t* wfH  = wcFL + (size_t)4 * 128 * 512;  // [4][128][128]
    ushort_t* wfL  = wfH + (size_t)4 * 128 * 128;
    ushort_t* weH  = wfL + (size_t)4 * 128 * 128;   // [1024][128]
    ushort_t* weL  = weH + (size_t)1024 * 128;
    float* biasF = (float*)(weL + (size_t)1024 * 128);  // [4][128]
    float* biasM = biasF + 512;                          // [4][128]
    float* stats = biasM + 512;                          // [25][4][2]

    hipMemsetAsync(stats, 0, 25 * 4 * 2 * sizeof(float), stream);

    cvt_split_kernel<<<dim3(256), 256, 0, stream>>>(w_exp, weH, weL, 1024 * 128);

    // front: GN(x) folded into w_comp
    stats_plain<<<dim3(512, 4), 256, 0, stream>>>(x, 512, stats);
    fold_kernel<512><<<dim3(16, 4), 256, 0, stream>>>(
        w_comp, gn_g, gn_b, stats, 1.f / (512.f * (float)LSEQ), wcFH, wcFL, biasF);
    gemm_mfma<512, 128, 1, 1, true, true, false, false><<<dim3(125, 1, 4), 256, 0, stream>>>(
        x, nullptr, nullptr, wcFH, wcFL, biasF, nullptr, bufA);

    float* cur = bufA;
    float* nxt = bufB;
    for (int i = 0; i < 24; i++) {
        int dil = 1 << (i & 7);
        float* st = stats + (size_t)(1 + i) * 8;
        conv_split_stats<<<dim3(25, 16, 4), 320, 0, stream>>>(
            cur, dw_w + (size_t)i * 384, pr_a + (size_t)i * 128, dil, hH, hL, st);
        fold_kernel<128><<<dim3(16, 4), 256, 0, stream>>>(
            pw_w + (size_t)i * 16384, tn_g + (size_t)i * 128, tn_b + (size_t)i * 128,
            st, 1.f / (128.f * (float)LSEQ), wfH, wfL, biasM);
        gemm_mfma<128, 128, 1, 0, true, true, true, false><<<dim3(125, 1, 4), 256, 0, stream>>>(
            nullptr, hH, hL, wfH, wfL, biasM, cur, nxt);
        float* tmp = cur; cur = nxt; nxt = tmp;
    }

    // back: expansion (128 -> 1024) + sigmoid, o-tiles looped in-block
    gemm_mfma<128, 1024, 8, 1, false, false, false, true><<<dim3(125, 1, 4), 256, 0, stream>>>(
        cur, nullptr, nullptr, weH, weL, nullptr, nullptr, out);
}